// Round 8
// baseline (534.570 us; speedup 1.0000x reference)
//
#include <hip/hip_runtime.h>
#include <hip/hip_bf16.h>
#include <math.h>

#define EMB 1024
#define HEADS 16
#define HEAD_DIM 64
#define FF_DIM 4096
#define SEQ 2048
#define BATCH 2
#define NTOK (BATCH * SEQ)   // 4096 rows
#define LN_EPS 1e-5f
#define QKV_N 3072
// fold softmax scale into q: 0.125 * log2(e)
#define Q_PRESCALE 0.18033688011112042f

typedef __attribute__((ext_vector_type(8))) short s8v;   // 8 bf16 (4 VGPRs)
typedef __attribute__((ext_vector_type(4))) float f4v;   // MFMA accumulator

__device__ __forceinline__ unsigned short f2bf(float f) {
    union { __hip_bfloat16 h; unsigned short u; } cv;
    cv.h = __float2bfloat16(f);
    return cv.u;
}

__device__ __forceinline__ float fast_exp2(float x) {
#if __has_builtin(__builtin_amdgcn_exp2f)
    return __builtin_amdgcn_exp2f(x);
#else
    return exp2f(x);
#endif
}

// gelu with exp2-based tanh (libm tanhf ~30 insts -> ~8; identical math)
__device__ __forceinline__ float gelu_f(float x) {
    const float c = 0.7978845608028654f;  // sqrt(2/pi)
    float y = c * (x + 0.044715f * x * x * x);
    float e = fast_exp2(y * 2.8853900817779268f);   // 2*log2(e)
    float t = 1.0f - 2.0f / (e + 1.0f);
    return 0.5f * x * (1.0f + t);
}

#define GLDS(gp, lp)                                                        \
    __builtin_amdgcn_global_load_lds(                                       \
        (const __attribute__((address_space(1))) void*)(gp),                \
        (__attribute__((address_space(3))) void*)(lp), 16, 0, 0)

// sync helpers (raw barrier: no compiler vmcnt(0) drain)
#define BAR()   do { __builtin_amdgcn_s_barrier(); __builtin_amdgcn_sched_barrier(0); } while (0)
#define LGKM0() do { asm volatile("s_waitcnt lgkmcnt(0)" ::: "memory"); __builtin_amdgcn_sched_barrier(0); } while (0)
#define VMCNT(n) do { asm volatile("s_waitcnt vmcnt(" #n ")" ::: "memory"); __builtin_amdgcn_sched_barrier(0); } while (0)

// ---------------- LayerNorm -> bf16 out ----------------------------------------------
__global__ __launch_bounds__(256) void ln_bf16_kernel(const float* __restrict__ x,
                                                      const float* __restrict__ scale,
                                                      const float* __restrict__ shift,
                                                      unsigned short* __restrict__ out) {
    int row = blockIdx.x;
    int tid = threadIdx.x;
    const float4 xv = ((const float4*)(x + (size_t)row * EMB))[tid];
    float s  = xv.x + xv.y + xv.z + xv.w;
    float ss = xv.x * xv.x + xv.y * xv.y + xv.z * xv.z + xv.w * xv.w;
    __shared__ float2 red[256];
    red[tid] = make_float2(s, ss);
    __syncthreads();
    for (int off = 128; off > 0; off >>= 1) {
        if (tid < off) {
            red[tid].x += red[tid + off].x;
            red[tid].y += red[tid + off].y;
        }
        __syncthreads();
    }
    float mean = red[0].x * (1.0f / EMB);
    float var  = red[0].y * (1.0f / EMB) - mean * mean;
    float rstd = rsqrtf(var + LN_EPS);
    float4 sc4 = ((const float4*)scale)[tid];
    float4 sh4 = ((const float4*)shift)[tid];
    ushort4 o;
    o.x = f2bf(sc4.x * (xv.x - mean) * rstd + sh4.x);
    o.y = f2bf(sc4.y * (xv.y - mean) * rstd + sh4.y);
    o.z = f2bf(sc4.z * (xv.z - mean) * rstd + sh4.z);
    o.w = f2bf(sc4.w * (xv.w - mean) * rstd + sh4.w);
    *(ushort4*)(out + (size_t)row * EMB + tid * 4) = o;
}

// ---------------- fused fp32 [K][N] -> bf16 [N][K] transpose-convert (ALL weights) ----
__device__ __forceinline__ void tconv_tile(const float* __restrict__ W,
                                           unsigned short* __restrict__ Wt,
                                           int K, int N, int bx, int by, int tid) {
    __shared__ float t[64][65];
    int n0 = bx * 64, k0 = by * 64;
#pragma unroll
    for (int it = 0; it < 4; ++it) {
        int f = tid + it * 256;
        int r = f >> 4, c = (f & 15) * 4;
        float4 w = *(const float4*)(W + (size_t)(k0 + r) * N + n0 + c);
        t[r][c] = w.x; t[r][c + 1] = w.y; t[r][c + 2] = w.z; t[r][c + 3] = w.w;
    }
    __syncthreads();
#pragma unroll
    for (int it = 0; it < 4; ++it) {
        int f = tid + it * 256;
        int rn = f >> 4, ck = (f & 15) * 4;
        ushort4 o;
        o.x = f2bf(t[ck + 0][rn]);
        o.y = f2bf(t[ck + 1][rn]);
        o.z = f2bf(t[ck + 2][rn]);
        o.w = f2bf(t[ck + 3][rn]);
        *(ushort4*)(Wt + (size_t)(n0 + rn) * K + k0 + ck) = o;
    }
}

__global__ __launch_bounds__(256) void tconv_all_kernel(
    const float* __restrict__ Wq, const float* __restrict__ Wk,
    const float* __restrict__ Wv, const float* __restrict__ Wo,
    const float* __restrict__ W1, const float* __restrict__ W2,
    unsigned short* __restrict__ Wqkv_t, unsigned short* __restrict__ Wo_t,
    unsigned short* __restrict__ W1_t, unsigned short* __restrict__ W2_t) {
    int b = blockIdx.x;
    int tid = threadIdx.x;
    if (b < 256)        tconv_tile(Wq, Wqkv_t,                      EMB, EMB,    b & 15, b >> 4, tid);
    else if (b < 512)   tconv_tile(Wk, Wqkv_t + (size_t)1024 * EMB, EMB, EMB,    (b - 256) & 15, (b - 256) >> 4, tid);
    else if (b < 768)   tconv_tile(Wv, Wqkv_t + (size_t)2048 * EMB, EMB, EMB,    (b - 512) & 15, (b - 512) >> 4, tid);
    else if (b < 1024)  tconv_tile(Wo, Wo_t,                        EMB, EMB,    (b - 768) & 15, (b - 768) >> 4, tid);
    else if (b < 2048)  tconv_tile(W1, W1_t,                        EMB, FF_DIM, (b - 1024) & 63, (b - 1024) >> 6, tid);
    else                tconv_tile(W2, W2_t,                        FF_DIM, EMB, (b - 2048) & 15, (b - 2048) >> 4, tid);
}

// ---------------- split-K reduce: out = p0 + p1 + bias + residual ---------------------
__global__ __launch_bounds__(256) void reduce_kernel(const float* __restrict__ p0,
                                                     const float* __restrict__ p1,
                                                     const float* __restrict__ bias,
                                                     const float* __restrict__ residual,
                                                     float* __restrict__ out) {
    size_t i4 = ((size_t)blockIdx.x * 256 + threadIdx.x) * 4;
    float4 a = *(const float4*)(p0 + i4);
    float4 b = *(const float4*)(p1 + i4);
    float4 r = *(const float4*)(residual + i4);
    int col = (int)(i4 & (EMB - 1));
    float4 bs = *(const float4*)(bias + col);
    float4 o;
    o.x = a.x + b.x + r.x + bs.x;
    o.y = a.y + b.y + r.y + bs.y;
    o.z = a.z + b.z + r.z + bs.z;
    o.w = a.w + b.w + r.w + bs.w;
    *(float4*)(out + i4) = o;
}

// ---------------- fused split-K reduce + LayerNorm ------------------------------------
__global__ __launch_bounds__(256) void reduce_ln_kernel(const float* __restrict__ p0,
                                                        const float* __restrict__ p1,
                                                        const float* __restrict__ bias,
                                                        const float* __restrict__ residual,
                                                        float* __restrict__ x1,
                                                        const float* __restrict__ scale,
                                                        const float* __restrict__ shift,
                                                        unsigned short* __restrict__ out) {
    int row = blockIdx.x;
    int tid = threadIdx.x;
    size_t i4 = (size_t)row * EMB + tid * 4;
    float4 a = *(const float4*)(p0 + i4);
    float4 b = *(const float4*)(p1 + i4);
    float4 r = *(const float4*)(residual + i4);
    float4 bs = *(const float4*)(bias + tid * 4);
    float4 xv;
    xv.x = a.x + b.x + r.x + bs.x;
    xv.y = a.y + b.y + r.y + bs.y;
    xv.z = a.z + b.z + r.z + bs.z;
    xv.w = a.w + b.w + r.w + bs.w;
    *(float4*)(x1 + i4) = xv;

    float s  = xv.x + xv.y + xv.z + xv.w;
    float ss = xv.x * xv.x + xv.y * xv.y + xv.z * xv.z + xv.w * xv.w;
    __shared__ float2 red[256];
    red[tid] = make_float2(s, ss);
    __syncthreads();
    for (int off = 128; off > 0; off >>= 1) {
        if (tid < off) {
            red[tid].x += red[tid + off].x;
            red[tid].y += red[tid + off].y;
        }
        __syncthreads();
    }
    float mean = red[0].x * (1.0f / EMB);
    float var  = red[0].y * (1.0f / EMB) - mean * mean;
    float rstd = rsqrtf(var + LN_EPS);
    float4 sc4 = ((const float4*)scale)[tid];
    float4 sh4 = ((const float4*)shift)[tid];
    ushort4 o;
    o.x = f2bf(sc4.x * (xv.x - mean) * rstd + sh4.x);
    o.y = f2bf(sc4.y * (xv.y - mean) * rstd + sh4.y);
    o.z = f2bf(sc4.z * (xv.z - mean) * rstd + sh4.z);
    o.w = f2bf(sc4.w * (xv.w - mean) * rstd + sh4.w);
    *(ushort4*)(out + i4) = o;
}

// ================= fused 128x128 bf16 MFMA GEMM -- REGISTER-DIRECT K-loop =============
// R7 resubmit (R7 bench was an infra failure, no measurement). Zero barriers, zero LDS
// in the K-loop. Every LDS-staged variant (R3/R5/R6/8ph) pinned at 420-430 TF,
// MfmaUtil 8-17%: the barrier-synced LDS round-trip serializes the slowest wave's
// memory latency into all waves every K-step. Here each wave loads its MFMA fragments
// directly global->VGPR (per-lane 16B, exact frag layout; A/B are L2-resident at these
// shapes so LDS sharing buys little), register-double-buffered one K-step ahead;
// waves fully independent -> 12 waves/CU of genuine TLP.
// K must be a multiple of 64. LDS used only for the coalesced store epilogue.
__global__ __launch_bounds__(256) void gemm_fused_kernel(
    const unsigned short* __restrict__ A,   // [M,K] bf16
    const unsigned short* __restrict__ Bt,  // [N,K] bf16
    unsigned short* __restrict__ Cb,        // bf16 out
    int M, int N, int K,
    const float* __restrict__ bias,
    int do_gelu, int qkv_mode,
    unsigned short* __restrict__ vt)
{
    __shared__ short lds[16384];   // 32 KiB, epilogue staging only

    int tid = threadIdx.x;
    // 1D bid -> (x = N-block, y = M-block) with y % 8 == XCD id (A-panel L2 colocation)
    int nbx = N >> 7, nby8 = (M >> 7) >> 3;
    int bid = (int)blockIdx.x;
    int xcd = bid & 7;
    int t   = bid >> 3;
    int x   = t % nbx;
    int u   = t / nbx;
    int y   = (u % nby8) * 8 + xcd;
    int m0 = y << 7, n0 = x << 7;

    int wv = tid >> 6, lane = tid & 63;
    int wr = wv >> 1, wc = wv & 1;
    int quad = lane >> 4, ln = lane & 15;

    f4v acc[4][4];
#pragma unroll
    for (int i = 0; i < 4; ++i)
#pragma unroll
        for (int j = 0; j < 4; ++j) { f4v z4 = {0.f, 0.f, 0.f, 0.f}; acc[i][j] = z4; }

    // per-lane fragment base pointers (A-frag lane l: row=l&15 (+i*16), k-chunk=(l>>4)*8)
    const unsigned short* Ap = A + (size_t)(m0 + wr * 64 + ln) * K + quad * 8;
    const unsigned short* Bp = Bt + (size_t)(n0 + wc * 64 + ln) * K + quad * 8;

    s8v a0[4], b0[4], a1[4], b1[4];

#define LOADF(da, db, koff) do {                                            \
    _Pragma("unroll") for (int i_ = 0; i_ < 4; ++i_) {                      \
        da[i_] = *(const s8v*)(Ap + (size_t)i_ * 16 * K + (koff));          \
        db[i_] = *(const s8v*)(Bp + (size_t)i_ * 16 * K + (koff)); } } while (0)
#define MFMA16(sa, sb) do {                                                 \
    _Pragma("unroll") for (int i_ = 0; i_ < 4; ++i_)                        \
    _Pragma("unroll") for (int j_ = 0; j_ < 4; ++j_)                        \
        acc[i_][j_] = __builtin_amdgcn_mfma_f32_16x16x32_bf16(              \
            sa[i_], sb[j_], acc[i_][j_], 0, 0, 0); } while (0)

    int nIter = K >> 5;          // even (K % 64 == 0)
    LOADF(a0, b0, 0);
    for (int it = 0; it < nIter; it += 2) {
        LOADF(a1, b1, (it + 1) * 32);         // prefetch next step (compiler counts waits)
        MFMA16(a0, b0);
        if (it + 2 < nIter) LOADF(a0, b0, (it + 2) * 32);
        MFMA16(a1, b1);
    }
#undef LOADF
#undef MFMA16

    // ==== epilogue: re-stage C (128x128 bf16 = 32 KiB) through LDS ====
    int colb = wc * 64 + ln;          // + j*16
    int rowb = wr * 64 + quad * 4;    // + i*16 (+ r)
    int off8 = (tid & 15) * 8;
    int sub  = tid >> 4;              // 0..15

    if (qkv_mode && n0 >= 2048) {
        // v -> vt transpose: column-major stage [col][row], XOR-swizzled rows
#pragma unroll
        for (int j = 0; j < 4; ++j) {
            int c = colb + j * 16;
            int swz = (c & 7) << 3;
#pragma unroll
            for (int i = 0; i < 4; ++i) {
                int rw = rowb + i * 16;
                ushort4 pk;
                pk.x = f2bf(acc[i][j][0]);
                pk.y = f2bf(acc[i][j][1]);
                pk.z = f2bf(acc[i][j][2]);
                pk.w = f2bf(acc[i][j][3]);
                *(ushort4*)(lds + c * 128 + (rw ^ swz)) = pk;
            }
        }
        BAR();
        int bb = m0 >> 11, s0b = m0 & 2047;
        size_t vbase = ((size_t)bb * 1024 + (n0 - 2048)) * SEQ + s0b + off8;
#pragma unroll
        for (int pass = 0; pass < 8; ++pass) {
            int c = pass * 16 + sub;
            s8v v = *(const s8v*)(lds + c * 128 + (off8 ^ ((c & 7) << 3)));
            *(s8v*)(vt + vbase + (size_t)c * SEQ) = v;
        }
        return;
    }

    // row-major stage [row][col], XOR-swizzled cols (q/k prescale or bias+gelu here)
    bool isq = qkv_mode && (n0 < 1024);
#pragma unroll
    for (int j = 0; j < 4; ++j) {
        int c = colb + j * 16;
        float bj = (!qkv_mode && bias) ? bias[n0 + c] : 0.f;
#pragma unroll
        for (int i = 0; i < 4; ++i) {
            int rw = rowb + i * 16;
#pragma unroll
            for (int r = 0; r < 4; ++r) {
                float vv = acc[i][j][r];
                if (qkv_mode) { if (isq) vv *= Q_PRESCALE; }
                else { vv += bj; if (do_gelu) vv = gelu_f(vv); }
                int rr_ = rw + r;
                lds[rr_ * 128 + (c ^ ((rr_ & 7) << 3))] = (short)f2bf(vv);
            }
        }
    }
    BAR();
    int ldc = qkv_mode ? 2048 : N;
#pragma unroll
    for (int pass = 0; pass < 8; ++pass) {
        int rw = pass * 16 + sub;
        s8v v = *(const s8v*)(lds + rw * 128 + (off8 ^ ((rw & 7) << 3)));
        *(s8v*)(Cb + (size_t)(m0 + rw) * ldc + n0 + off8) = v;
    }
}

// ---------------- bf16 MFMA GEMM, 128x128 split-K fp32, BK=32, DEPTH-2 ----------------
// (unchanged from R6 -- control group for the reg-direct experiment)
__global__ __launch_bounds__(256) void gemm_bf16_kernel(
    const unsigned short* __restrict__ A,   // [M,K] bf16
    const unsigned short* __restrict__ Bt,  // [N,K] bf16
    float* __restrict__ Cf0,
    float* __restrict__ Cf1,
    int M, int N, int K, int Klen)
{
    __shared__ short As[3][4096];
    __shared__ short Bs[3][4096];

    int tid = threadIdx.x;
    int nbx = N >> 7, nby8 = (M >> 7) >> 3;
    int bid = (int)blockIdx.x;
    int xcd = bid & 7;
    int t   = bid >> 3;
    int x   = t % nbx;
    int u   = t / nbx;
    int y   = (u % nby8) * 8 + xcd;
    int z   = u / nby8;

    int m0 = y << 7;
    int n0 = x << 7;
    int k0 = z * Klen;
    float* Cf = z ? Cf1 : Cf0;
    int wv = tid >> 6, lane = tid & 63;
    int wr = wv >> 1, wc = wv & 1;
    int quad = lane >> 4, ln = lane & 15;

    f4v acc[4][4];
#pragma unroll
    for (int i = 0; i < 4; ++i)
#pragma unroll
        for (int j = 0; j < 4; ++j) {
            f4v z4 = {0.f, 0.f, 0.f, 0.f};
            acc[i][j] = z4;
        }

    int r0 = tid & 127;
    size_t Kby = (size_t)K << 1;
    const char* Ag0 = (const char*)A + (size_t)(m0 + r0) * Kby + (size_t)k0 * 2 + (tid >> 7) * 16;
    const char* Bg0 = (const char*)Bt + (size_t)(n0 + r0) * Kby + (size_t)k0 * 2 + (tid >> 7) * 16;

#define STAGE(tt, bi) do {                                                  \
    int kb_ = (tt) << 6;                                                    \
    char* Ad_ = (char*)As[bi] + tid * 16;                                   \
    char* Bd_ = (char*)Bs[bi] + tid * 16;                                   \
    GLDS(Ag0 + kb_, Ad_); GLDS(Ag0 + kb_ + 32, Ad_ + 4096);                 \
    GLDS(Bg0 + kb_, Bd_); GLDS(Bg0 + kb_ + 32, Bd_ + 4096); } while (0)

    int nIter = Klen >> 5;   // 16 (Wo) / 64 (W2)
    STAGE(0, 0);
    STAGE(1, 1);

    int cur = 0, stg = 2;
    for (int it = 0; it < nIter; ++it) {
        if (it + 1 < nIter) { VMCNT(4); } else { VMCNT(0); }
        BAR();
        if (it + 2 < nIter) {
            STAGE(it + 2, stg);
            __builtin_amdgcn_sched_barrier(0);
        }
        const short* Ab = As[cur];
        const short* Bb = Bs[cur];
        s8v af[4], bfr[4];
#pragma unroll
        for (int i = 0; i < 4; ++i)
            af[i] = *(const s8v*)(Ab + ((size_t)quad * 128 + wr * 64 + i * 16 + ln) * 8);
#pragma unroll
        for (int j = 0; j < 4; ++j)
            bfr[j] = *(const s8v*)(Bb + ((size_t)quad * 128 + wc * 64 + j * 16 + ln) * 8);
#pragma unroll
        for (int i = 0; i < 4; ++i)
#pragma unroll
            for (int j = 0; j < 4; ++j)
                acc[i][j] = __builtin_amdgcn_mfma_f32_16x16x32_bf16(af[i], bfr[j], acc[i][j], 0, 0, 0);
        cur = (cur == 2) ? 0 : cur + 1;
        stg = (stg == 2) ? 0 : stg + 1;
    }
#undef STAGE

    int cn  = n0 + wc * 64 + ln;
    int cm0 = m0 + wr * 64 + quad * 4;
#pragma unroll
    for (int j = 0; j < 4; ++j) {
        int gn = cn + j * 16;
#pragma unroll
        for (int i = 0; i < 4; ++i)
#pragma unroll
            for (int r = 0; r < 4; ++r)
                Cf[(size_t)(cm0 + i * 16 + r) * N + gn] = acc[i][j][r];
    }
}

// ---------------- double-buffered MFMA flash attention (unchanged from R2) ------------
__global__ __launch_bounds__(256) void flash_attn_mfma_kernel(
    const unsigned short* __restrict__ qk,   // [NTOK][2048]  (q*scale | k per head)
    const unsigned short* __restrict__ vt,   // [B*1024][SEQ] (v transposed)
    unsigned short* __restrict__ ctx)        // [NTOK][EMB]
{
    int h  = blockIdx.x;
    int b  = blockIdx.z;
    int qt = b ? (int)blockIdx.y : ((int)gridDim.y - 1 - (int)blockIdx.y);
    int tid = threadIdx.x;
    int w = tid >> 6, lane = tid & 63;
    int quad = lane >> 4, ln = lane & 15;

    __shared__ short Kb2[2][4096];
    __shared__ short Vb2[2][4096];
    __shared__ short Ps[4][32 * 72];

    size_t qrow0 = (size_t)b * SEQ + (size_t)qt * 128;
    int wrow0 = w * 32;

    s8v qf[2][2];
#pragma unroll
    for (int mb = 0; mb < 2; ++mb)
#pragma unroll
        for (int ks = 0; ks < 2; ++ks)
            qf[mb][ks] = *(const s8v*)(qk + (qrow0 + wrow0 + mb * 16 + ln) * 2048
                                          + h * 64 + ks * 32 + quad * 8);

    float l_part[2][4];
    f4v o[2][4];
#pragma unroll
    for (int mb = 0; mb < 2; ++mb) {
#pragma unroll
        for (int r = 0; r < 4; ++r) l_part[mb][r] = 0.f;
#pragma unroll
        for (int db = 0; db < 4; ++db) {
            f4v z = {0.f, 0.f, 0.f, 0.f};
            o[mb][db] = z;
        }
    }

    const unsigned short* kb_p = qk + (size_t)b * SEQ * 2048 + 1024 + h * 64;
    const unsigned short* vb_p = vt + ((size_t)b * 1024 + h * 64) * SEQ;
    short* Pw = Ps[w];

    int rr = tid & 63;
    const unsigned short* Kg0 = kb_p + (size_t)rr * 2048 + (tid >> 6) * 8;
    const unsigned short* Vg0 = vb_p + (size_t)rr * 2048 + (tid >> 6) * 8;

    int ktn = 2 * qt + 2;
    int ktmax_w = (qt * 128 + wrow0 + 31) >> 6;

    GLDS(Kg0, (char*)Kb2[0] + tid * 16);
    GLDS(Kg0 + 32, (char*)Kb2[0] + tid * 16 + 4096);
    GLDS(Vg0, (char*)Vb2[0] + tid * 16);
    GLDS(Vg0 + 32, (char*)Vb2[0] + tid * 16 + 4096);

    for (int kt = 0; kt < ktn; ++kt) {
        BAR();
        bool pf = (kt + 1 < ktn);
        if (pf) {
            int nb_ = (kt + 1) & 1;
            const unsigned short* ks_ = Kg0 + (size_t)(kt + 1) * 64 * 2048;
            const unsigned short* vs_ = Vg0 + (kt + 1) * 64;
            GLDS(ks_, (char*)Kb2[nb_] + tid * 16);
            GLDS(ks_ + 32, (char*)Kb2[nb_] + tid * 16 + 4096);
            GLDS(vs_, (char*)Vb2[nb_] + tid * 16);
            GLDS(vs_ + 32, (char*)Vb2[nb_] + tid * 16 + 4096);
        }
        if (kt > ktmax_w) continue;
        if (pf) { VMCNT(8); } else { VMCNT(0); }

        const short* Kl = Kb2[kt & 1];
        const short* Vl = Vb2[kt & 1];

        f4v s[2][4];
#pragma unroll
        for (int mb = 0; mb < 2; ++mb)
#pragma unroll
            for (int nb = 0; nb < 4; ++nb) {
                f4v z = {0.f, 0.f, 0.f, 0.f};
                s[mb][nb] = z;
            }
#pragma unroll
        for (int ks = 0; ks < 2; ++ks)
#pragma unroll
            for (int nb = 0; nb < 4; ++nb) {
                s8v kfr = *(const s8v*)(Kl + ((size_t)(ks * 4 + quad) * 64 + nb * 16 + ln) * 8);
#pragma unroll
                for (int mb = 0; mb < 2; ++mb)
                    s[mb][nb] = __builtin_amdgcn_mfma_f32_16x16x32_bf16(qf[mb][ks], kfr, s[mb][nb], 0, 0, 0);
            }

        bool edge = (kt == ktmax_w);
#pragma unroll
        for (int mb = 0; mb < 2; ++mb) {
#pragma unroll
            for (int r = 0; r < 4; ++r) {
                int rloc = mb * 16 + quad * 4 + r;
                float p[4];
                if (!edge) {
#pragma unroll
                    for (int nb = 0; nb < 4; ++nb)
                        p[nb] = fast_exp2(s[mb][nb][r]);
                } else {
                    int grow = qt * 128 + wrow0 + rloc;
#pragma unroll
                    for (int nb = 0; nb < 4; ++nb) {
                        int key = kt * 64 + nb * 16 + ln;
                        float e = fast_exp2(s[mb][nb][r]);
                        p[nb] = (key > grow) ? 0.f : e;
                    }
                }
                l_part[mb][r] += (p[0] + p[1]) + (p[2] + p[3]);
#pragma unroll
                for (int nb = 0; nb < 4; ++nb)
                    Pw[rloc * 72 + nb * 16 + ln] = f2bf(p[nb]);
            }
        }

#pragma unroll
        for (int ks = 0; ks < 2; ++ks) {
            s8v pf_[2];
#pragma unroll
            for (int mb = 0; mb < 2; ++mb)
                pf_[mb] = *(const s8v*)(Pw + (mb * 16 + ln) * 72 + ks * 32 + quad * 8);
#pragma unroll
            for (int db = 0; db < 4; ++db) {
                s8v vfr = *(const s8v*)(Vl + ((size_t)(ks * 4 + quad) * 64 + db * 16 + ln) * 8);
#pragma unroll
                for (int mb = 0; mb < 2; ++mb)
                    o[mb][db] = __builtin_amdgcn_mfma_f32_16x16x32_bf16(pf_[mb], vfr, o[mb][db], 0, 0, 0);
            }
        }
    }

    asm volatile("s_waitcnt vmcnt(0)" ::: "memory");

#pragma unroll
    for (int mb = 0; mb < 2; ++mb)
#pragma unroll
        for (int r = 0; r < 4; ++r) {
            float l = l_part[mb][r];
#pragma unroll
            for (int msk = 1; msk < 16; msk <<= 1)
                l += __shfl_xor(l, msk);
            float inv = 1.0f / l;
            size_t row = qrow0 + wrow0 + mb * 16 + quad * 4 + r;
#pragma unroll
            for (int db = 0; db < 4; ++db)
                ctx[row * EMB + h * 64 + db * 16 + ln] = f2bf(o[mb][db][r] * inv);
        }
}

extern "C" void kernel_launch(void* const* d_in, const int* in_sizes, int n_in,
                              void* d_out, int out_size, void* d_ws, size_t ws_size,
                              hipStream_t stream) {
    const float* x    = (const float*)d_in[0];
    const float* Wq   = (const float*)d_in[1];
    const float* Wk   = (const float*)d_in[2];
    const float* Wv   = (const float*)d_in[3];
    const float* Wo   = (const float*)d_in[4];
    const float* bo   = (const float*)d_in[5];
    const float* W1   = (const float*)d_in[6];
    const float* b1   = (const float*)d_in[7];
    const float* W2   = (const float*)d_in[8];
    const float* b2   = (const float*)d_in[9];
    const float* ln1s = (const float*)d_in[10];
    const float* ln1b = (const float*)d_in[11];
    const float* ln2s = (const float*)d_in[12];
    const float* ln2b = (const float*)d_in[13];
    float* out = (float*)d_out;

    const size_t MiB = 1024 * 1024;
    uint8_t* w8 = (uint8_t*)d_ws;
    unsigned short* Wqkv_t = (unsigned short*)(w8);             //  0..6   [3072][1024]
    unsigned short* Wo_t   = (unsigned short*)(w8 +  6 * MiB);  //  6..8   [1024][1024]
    unsigned short* W1_t   = (unsigned short*)(w8 +  8 * MiB);  //  8..16  [4096][1024]
    unsigned short* W2_t   = (unsigned short*)(w8 + 16 * MiB);  // 16..24  [1024][4096]
    unsigned short* act_bf = (unsigned short*)(w8 + 24 * MiB);  // 24..32  h1/ctx/h2
    unsigned short* qk_bf  = (unsigned short*)(w8 + 32 * MiB);  // 32..48  [4096][2048]
    unsigned short* vt     = (unsigned short*)(w8 + 48 * MiB);  // 48..56  [2048][2048]
    float*          p0a    = (float*)(w8 + 32 * MiB);           // 32..48  (after attn)
    float*          p1a    = (float*)(w8 + 48 * MiB);           // 48..64
    unsigned short* u_bf   = (unsigned short*)(w8 + 32 * MiB);  // 32..64  (step 6+)
    float*          x1     = (float*)(w8 + 64 * MiB);           // 64..80
    float*          p0b    = (float*)(w8);                      //  0..16  (weights dead)
    float*          p1b    = (float*)(w8 + 80 * MiB);           // 80..96

    // 0) all weight converts in one dispatch
    tconv_all_kernel<<<3072, 256, 0, stream>>>(Wq, Wk, Wv, Wo, W1, W2,
                                               Wqkv_t, Wo_t, W1_t, W2_t);

    // 1) LN1 -> bf16
    ln_bf16_kernel<<<NTOK, 256, 0, stream>>>(x, ln1s, ln1b, act_bf);

    // 2) fused QKV (128^2 reg-direct; q prescaled, v -> vt)  768 blocks
    gemm_fused_kernel<<<(NTOK / 128) * (QKV_N / 128), 256, 0, stream>>>(
        act_bf, Wqkv_t, qk_bf, NTOK, QKV_N, EMB, nullptr, 0, 1, vt);

    // 3) double-buffered MFMA flash attention -> ctx bf16
    flash_attn_mfma_kernel<<<dim3(HEADS, SEQ / 128, BATCH), 256, 0, stream>>>(qk_bf, vt, act_bf);

    // 4+5) x1 = x + ctx @ Wo + bo (split-K2, depth-2); fused reduce+LN2
    gemm_bf16_kernel<<<(EMB / 128) * (NTOK / 128) * 2, 256, 0, stream>>>(
        act_bf, Wo_t, p0a, p1a, NTOK, EMB, EMB, 512);
    reduce_ln_kernel<<<NTOK, 256, 0, stream>>>(p0a, p1a, bo, x, x1, ln2s, ln2b, act_bf);

    // 6) u = gelu(h2 @ W1 + b1) -> bf16  (128^2 reg-direct)  1024 blocks
    gemm_fused_kernel<<<(NTOK / 128) * (FF_DIM / 128), 256, 0, stream>>>(
        act_bf, W1_t, u_bf, NTOK, FF_DIM, EMB, b1, 1, 0, nullptr);

    // 7) out = x1 + u @ W2 + b2   (split-K2, depth-2)
    gemm_bf16_kernel<<<(EMB / 128) * (NTOK / 128) * 2, 256, 0, stream>>>(
        u_bf, W2_t, p0b, p1b, NTOK, EMB, FF_DIM, 2048);
    reduce_kernel<<<(NTOK * EMB) / 1024, 256, 0, stream>>>(p0b, p1b, b2, x1, out);
}

// Round 9
// 449.863 us; speedup vs baseline: 1.1883x; 1.1883x over previous
//
#include <hip/hip_runtime.h>
#include <hip/hip_bf16.h>
#include <math.h>

#define EMB 1024
#define HEADS 16
#define HEAD_DIM 64
#define FF_DIM 4096
#define SEQ 2048
#define BATCH 2
#define NTOK (BATCH * SEQ)   // 4096 rows
#define LN_EPS 1e-5f
#define QKV_N 3072
// fold softmax scale into q: 0.125 * log2(e)
#define Q_PRESCALE 0.18033688011112042f

typedef __attribute__((ext_vector_type(8))) short s8v;   // 8 bf16 (4 VGPRs)
typedef __attribute__((ext_vector_type(4))) float f4v;   // MFMA accumulator

__device__ __forceinline__ unsigned short f2bf(float f) {
    union { __hip_bfloat16 h; unsigned short u; } cv;
    cv.h = __float2bfloat16(f);
    return cv.u;
}

__device__ __forceinline__ float fast_exp2(float x) {
#if __has_builtin(__builtin_amdgcn_exp2f)
    return __builtin_amdgcn_exp2f(x);
#else
    return exp2f(x);
#endif
}

// gelu with exp2-based tanh (libm tanhf ~30 insts -> ~8; identical math)
__device__ __forceinline__ float gelu_f(float x) {
    const float c = 0.7978845608028654f;  // sqrt(2/pi)
    float y = c * (x + 0.044715f * x * x * x);
    float e = fast_exp2(y * 2.8853900817779268f);   // 2*log2(e)
    float t = 1.0f - 2.0f / (e + 1.0f);
    return 0.5f * x * (1.0f + t);
}

#define GLDS(gp, lp)                                                        \
    __builtin_amdgcn_global_load_lds(                                       \
        (const __attribute__((address_space(1))) void*)(gp),                \
        (__attribute__((address_space(3))) void*)(lp), 16, 0, 0)

// sync helpers (raw barrier: no compiler vmcnt(0) drain)
#define BAR()   do { __builtin_amdgcn_s_barrier(); __builtin_amdgcn_sched_barrier(0); } while (0)
#define LGKM0() do { asm volatile("s_waitcnt lgkmcnt(0)" ::: "memory"); __builtin_amdgcn_sched_barrier(0); } while (0)
#define VMCNT(n) do { asm volatile("s_waitcnt vmcnt(" #n ")" ::: "memory"); __builtin_amdgcn_sched_barrier(0); } while (0)

// ---------------- LayerNorm -> bf16 out ----------------------------------------------
__global__ __launch_bounds__(256) void ln_bf16_kernel(const float* __restrict__ x,
                                                      const float* __restrict__ scale,
                                                      const float* __restrict__ shift,
                                                      unsigned short* __restrict__ out) {
    int row = blockIdx.x;
    int tid = threadIdx.x;
    const float4 xv = ((const float4*)(x + (size_t)row * EMB))[tid];
    float s  = xv.x + xv.y + xv.z + xv.w;
    float ss = xv.x * xv.x + xv.y * xv.y + xv.z * xv.z + xv.w * xv.w;
    __shared__ float2 red[256];
    red[tid] = make_float2(s, ss);
    __syncthreads();
    for (int off = 128; off > 0; off >>= 1) {
        if (tid < off) {
            red[tid].x += red[tid + off].x;
            red[tid].y += red[tid + off].y;
        }
        __syncthreads();
    }
    float mean = red[0].x * (1.0f / EMB);
    float var  = red[0].y * (1.0f / EMB) - mean * mean;
    float rstd = rsqrtf(var + LN_EPS);
    float4 sc4 = ((const float4*)scale)[tid];
    float4 sh4 = ((const float4*)shift)[tid];
    ushort4 o;
    o.x = f2bf(sc4.x * (xv.x - mean) * rstd + sh4.x);
    o.y = f2bf(sc4.y * (xv.y - mean) * rstd + sh4.y);
    o.z = f2bf(sc4.z * (xv.z - mean) * rstd + sh4.z);
    o.w = f2bf(sc4.w * (xv.w - mean) * rstd + sh4.w);
    *(ushort4*)(out + (size_t)row * EMB + tid * 4) = o;
}

// ---------------- fused fp32 [K][N] -> bf16 [N][K] transpose-convert (ALL weights) ----
__device__ __forceinline__ void tconv_tile(const float* __restrict__ W,
                                           unsigned short* __restrict__ Wt,
                                           int K, int N, int bx, int by, int tid) {
    __shared__ float t[64][65];
    int n0 = bx * 64, k0 = by * 64;
#pragma unroll
    for (int it = 0; it < 4; ++it) {
        int f = tid + it * 256;
        int r = f >> 4, c = (f & 15) * 4;
        float4 w = *(const float4*)(W + (size_t)(k0 + r) * N + n0 + c);
        t[r][c] = w.x; t[r][c + 1] = w.y; t[r][c + 2] = w.z; t[r][c + 3] = w.w;
    }
    __syncthreads();
#pragma unroll
    for (int it = 0; it < 4; ++it) {
        int f = tid + it * 256;
        int rn = f >> 4, ck = (f & 15) * 4;
        ushort4 o;
        o.x = f2bf(t[ck + 0][rn]);
        o.y = f2bf(t[ck + 1][rn]);
        o.z = f2bf(t[ck + 2][rn]);
        o.w = f2bf(t[ck + 3][rn]);
        *(ushort4*)(Wt + (size_t)(n0 + rn) * K + k0 + ck) = o;
    }
}

__global__ __launch_bounds__(256) void tconv_all_kernel(
    const float* __restrict__ Wq, const float* __restrict__ Wk,
    const float* __restrict__ Wv, const float* __restrict__ Wo,
    const float* __restrict__ W1, const float* __restrict__ W2,
    unsigned short* __restrict__ Wqkv_t, unsigned short* __restrict__ Wo_t,
    unsigned short* __restrict__ W1_t, unsigned short* __restrict__ W2_t) {
    int b = blockIdx.x;
    int tid = threadIdx.x;
    if (b < 256)        tconv_tile(Wq, Wqkv_t,                      EMB, EMB,    b & 15, b >> 4, tid);
    else if (b < 512)   tconv_tile(Wk, Wqkv_t + (size_t)1024 * EMB, EMB, EMB,    (b - 256) & 15, (b - 256) >> 4, tid);
    else if (b < 768)   tconv_tile(Wv, Wqkv_t + (size_t)2048 * EMB, EMB, EMB,    (b - 512) & 15, (b - 512) >> 4, tid);
    else if (b < 1024)  tconv_tile(Wo, Wo_t,                        EMB, EMB,    (b - 768) & 15, (b - 768) >> 4, tid);
    else if (b < 2048)  tconv_tile(W1, W1_t,                        EMB, FF_DIM, (b - 1024) & 63, (b - 1024) >> 6, tid);
    else                tconv_tile(W2, W2_t,                        FF_DIM, EMB, (b - 2048) & 15, (b - 2048) >> 4, tid);
}

// ---------------- split-K reduce: out = p0 + p1 + bias + residual ---------------------
__global__ __launch_bounds__(256) void reduce_kernel(const float* __restrict__ p0,
                                                     const float* __restrict__ p1,
                                                     const float* __restrict__ bias,
                                                     const float* __restrict__ residual,
                                                     float* __restrict__ out) {
    size_t i4 = ((size_t)blockIdx.x * 256 + threadIdx.x) * 4;
    float4 a = *(const float4*)(p0 + i4);
    float4 b = *(const float4*)(p1 + i4);
    float4 r = *(const float4*)(residual + i4);
    int col = (int)(i4 & (EMB - 1));
    float4 bs = *(const float4*)(bias + col);
    float4 o;
    o.x = a.x + b.x + r.x + bs.x;
    o.y = a.y + b.y + r.y + bs.y;
    o.z = a.z + b.z + r.z + bs.z;
    o.w = a.w + b.w + r.w + bs.w;
    *(float4*)(out + i4) = o;
}

// ---------------- fused split-K reduce + LayerNorm ------------------------------------
__global__ __launch_bounds__(256) void reduce_ln_kernel(const float* __restrict__ p0,
                                                        const float* __restrict__ p1,
                                                        const float* __restrict__ bias,
                                                        const float* __restrict__ residual,
                                                        float* __restrict__ x1,
                                                        const float* __restrict__ scale,
                                                        const float* __restrict__ shift,
                                                        unsigned short* __restrict__ out) {
    int row = blockIdx.x;
    int tid = threadIdx.x;
    size_t i4 = (size_t)row * EMB + tid * 4;
    float4 a = *(const float4*)(p0 + i4);
    float4 b = *(const float4*)(p1 + i4);
    float4 r = *(const float4*)(residual + i4);
    float4 bs = *(const float4*)(bias + tid * 4);
    float4 xv;
    xv.x = a.x + b.x + r.x + bs.x;
    xv.y = a.y + b.y + r.y + bs.y;
    xv.z = a.z + b.z + r.z + bs.z;
    xv.w = a.w + b.w + r.w + bs.w;
    *(float4*)(x1 + i4) = xv;

    float s  = xv.x + xv.y + xv.z + xv.w;
    float ss = xv.x * xv.x + xv.y * xv.y + xv.z * xv.z + xv.w * xv.w;
    __shared__ float2 red[256];
    red[tid] = make_float2(s, ss);
    __syncthreads();
    for (int off = 128; off > 0; off >>= 1) {
        if (tid < off) {
            red[tid].x += red[tid + off].x;
            red[tid].y += red[tid + off].y;
        }
        __syncthreads();
    }
    float mean = red[0].x * (1.0f / EMB);
    float var  = red[0].y * (1.0f / EMB) - mean * mean;
    float rstd = rsqrtf(var + LN_EPS);
    float4 sc4 = ((const float4*)scale)[tid];
    float4 sh4 = ((const float4*)shift)[tid];
    ushort4 o;
    o.x = f2bf(sc4.x * (xv.x - mean) * rstd + sh4.x);
    o.y = f2bf(sc4.y * (xv.y - mean) * rstd + sh4.y);
    o.z = f2bf(sc4.z * (xv.z - mean) * rstd + sh4.z);
    o.w = f2bf(sc4.w * (xv.w - mean) * rstd + sh4.w);
    *(ushort4*)(out + i4) = o;
}

// ================= fused 128x128 bf16 MFMA GEMM, BK=32, DEPTH-2 pipeline ==============
// R9: back to the R6 depth-2 LDS version -- best measured for QKV/FFN1 (85us FFN1,
// MfmaUtil 16). R8's register-direct variant was decisively worse (138us, MfmaUtil 10:
// compiler sank loads next to uses, killing the pipeline; stride-K per-lane gather).
__global__ __launch_bounds__(256) void gemm_fused_kernel(
    const unsigned short* __restrict__ A,   // [M,K] bf16
    const unsigned short* __restrict__ Bt,  // [N,K] bf16
    unsigned short* __restrict__ Cb,        // bf16 out
    int M, int N, int K,
    const float* __restrict__ bias,
    int do_gelu, int qkv_mode,
    unsigned short* __restrict__ vt)
{
    __shared__ short lds[24576];   // 48 KiB: As 3x8KB | Bs 3x8KB; epilogue reuses 32KB
    short* As = lds;               // buf b at shorts [b*4096, ...)
    short* Bs = lds + 12288;

    int tid = threadIdx.x;
    // 1D bid -> (x = N-block, y = M-block) with y % 8 == XCD id (A-panel L2 colocation)
    int nbx = N >> 7, nby8 = (M >> 7) >> 3;
    int bid = (int)blockIdx.x;
    int xcd = bid & 7;
    int t   = bid >> 3;
    int x   = t % nbx;
    int u   = t / nbx;
    int y   = (u % nby8) * 8 + xcd;
    int m0 = y << 7, n0 = x << 7;

    int wv = tid >> 6, lane = tid & 63;
    int wr = wv >> 1, wc = wv & 1;
    int quad = lane >> 4, ln = lane & 15;

    f4v acc[4][4];
#pragma unroll
    for (int i = 0; i < 4; ++i)
#pragma unroll
        for (int j = 0; j < 4; ++j) { f4v z4 = {0.f, 0.f, 0.f, 0.f}; acc[i][j] = z4; }

    int r0 = tid & 127;
    size_t Kby = (size_t)K << 1;
    const char* Ag0 = (const char*)A + (size_t)(m0 + r0) * Kby + (size_t)((tid >> 7) << 4);
    const char* Bg0 = (const char*)Bt + (size_t)(n0 + r0) * Kby + (size_t)((tid >> 7) << 4);

#define STAGE(tt, bi) do {                                                  \
    int kb_ = (tt) << 6;                                                    \
    char* Ad_ = (char*)As + (bi) * 8192 + tid * 16;                         \
    char* Bd_ = (char*)Bs + (bi) * 8192 + tid * 16;                         \
    GLDS(Ag0 + kb_, Ad_); GLDS(Ag0 + kb_ + 32, Ad_ + 4096);                 \
    GLDS(Bg0 + kb_, Bd_); GLDS(Bg0 + kb_ + 32, Bd_ + 4096); } while (0)

    int nIter = K >> 5;   // >= 2 for all call sites (K=1024)
    STAGE(0, 0);
    STAGE(1, 1);

    int cur = 0, stg = 2;
    for (int it = 0; it < nIter; ++it) {
        if (it + 1 < nIter) { VMCNT(4); } else { VMCNT(0); }
        BAR();
        if (it + 2 < nIter) {
            STAGE(it + 2, stg);
            __builtin_amdgcn_sched_barrier(0);
        }
        const short* Ab = As + cur * 4096;
        const short* Bb = Bs + cur * 4096;
        s8v af[4], bfr[4];
#pragma unroll
        for (int i = 0; i < 4; ++i)
            af[i] = *(const s8v*)(Ab + ((size_t)quad * 128 + wr * 64 + i * 16 + ln) * 8);
#pragma unroll
        for (int j = 0; j < 4; ++j)
            bfr[j] = *(const s8v*)(Bb + ((size_t)quad * 128 + wc * 64 + j * 16 + ln) * 8);
#pragma unroll
        for (int i = 0; i < 4; ++i)
#pragma unroll
            for (int j = 0; j < 4; ++j)
                acc[i][j] = __builtin_amdgcn_mfma_f32_16x16x32_bf16(af[i], bfr[j], acc[i][j], 0, 0, 0);
        cur = (cur == 2) ? 0 : cur + 1;
        stg = (stg == 2) ? 0 : stg + 1;
    }
#undef STAGE

    // ==== epilogue: re-stage C (128x128 bf16 = 32 KiB) through LDS ====
    LGKM0();
    BAR();        // everyone's frag reads done -> safe to overwrite lds

    int colb = wc * 64 + ln;          // + j*16
    int rowb = wr * 64 + quad * 4;    // + i*16 (+ r)
    int off8 = (tid & 15) * 8;
    int sub  = tid >> 4;              // 0..15

    if (qkv_mode && n0 >= 2048) {
        // v -> vt transpose: column-major stage [col][row], XOR-swizzled rows
#pragma unroll
        for (int j = 0; j < 4; ++j) {
            int c = colb + j * 16;
            int swz = (c & 7) << 3;
#pragma unroll
            for (int i = 0; i < 4; ++i) {
                int rw = rowb + i * 16;
                ushort4 pk;
                pk.x = f2bf(acc[i][j][0]);
                pk.y = f2bf(acc[i][j][1]);
                pk.z = f2bf(acc[i][j][2]);
                pk.w = f2bf(acc[i][j][3]);
                *(ushort4*)(lds + c * 128 + (rw ^ swz)) = pk;
            }
        }
        BAR();
        int bb = m0 >> 11, s0b = m0 & 2047;
        size_t vbase = ((size_t)bb * 1024 + (n0 - 2048)) * SEQ + s0b + off8;
#pragma unroll
        for (int pass = 0; pass < 8; ++pass) {
            int c = pass * 16 + sub;
            s8v v = *(const s8v*)(lds + c * 128 + (off8 ^ ((c & 7) << 3)));
            *(s8v*)(vt + vbase + (size_t)c * SEQ) = v;
        }
        return;
    }

    // row-major stage [row][col], XOR-swizzled cols (q/k prescale or bias+gelu here)
    bool isq = qkv_mode && (n0 < 1024);
#pragma unroll
    for (int j = 0; j < 4; ++j) {
        int c = colb + j * 16;
        float bj = (!qkv_mode && bias) ? bias[n0 + c] : 0.f;
#pragma unroll
        for (int i = 0; i < 4; ++i) {
            int rw = rowb + i * 16;
#pragma unroll
            for (int r = 0; r < 4; ++r) {
                float vv = acc[i][j][r];
                if (qkv_mode) { if (isq) vv *= Q_PRESCALE; }
                else { vv += bj; if (do_gelu) vv = gelu_f(vv); }
                int rr_ = rw + r;
                lds[rr_ * 128 + (c ^ ((rr_ & 7) << 3))] = (short)f2bf(vv);
            }
        }
    }
    BAR();
    int ldc = qkv_mode ? 2048 : N;
#pragma unroll
    for (int pass = 0; pass < 8; ++pass) {
        int rw = pass * 16 + sub;
        s8v v = *(const s8v*)(lds + rw * 128 + (off8 ^ ((rw & 7) << 3)));
        *(s8v*)(Cb + (size_t)(m0 + rw) * ldc + n0 + off8) = v;
    }
}

// ---------------- bf16 MFMA GEMM, double-buffered BK=32, 128x128 (split-K fp32) -------
// R9: reverted to the EXACT R2-measured version (81us W2, the session best for this
// call site). R3's stage-after-barrier, R4's BK=64, and R6's depth-2 variants all
// measured-or-inferred worse on this kernel (88 / ~100+). 2D grid, __syncthreads.
__global__ __launch_bounds__(256) void gemm_bf16_kernel(
    const unsigned short* __restrict__ A,   // [M,K] bf16
    const unsigned short* __restrict__ Bt,  // [N,K] bf16
    float* __restrict__ Cf0,
    float* __restrict__ Cf1,
    int M, int N, int K, int Klen)
{
    __shared__ short As[2][4096];   // 8 KiB per buffer
    __shared__ short Bs[2][4096];

    int tid = threadIdx.x;
    int m0 = blockIdx.y * 128;
    int n0 = blockIdx.x * 128;
    int k0 = blockIdx.z * Klen;
    float* Cf = blockIdx.z ? Cf1 : Cf0;
    int wv = tid >> 6, lane = tid & 63;
    int wr = wv >> 1, wc = wv & 1;
    int quad = lane >> 4, ln = lane & 15;

    f4v acc[4][4];
#pragma unroll
    for (int i = 0; i < 4; ++i)
#pragma unroll
        for (int j = 0; j < 4; ++j) {
            f4v z = {0.f, 0.f, 0.f, 0.f};
            acc[i][j] = z;
        }

    int r0 = tid & 127;
    size_t Kby = (size_t)K << 1;
    const char* Ag0 = (const char*)A + (size_t)(m0 + r0) * Kby + (size_t)k0 * 2 + (tid >> 7) * 16;
    const char* Bg0 = (const char*)Bt + (size_t)(n0 + r0) * Kby + (size_t)k0 * 2 + (tid >> 7) * 16;

    int nIter = Klen >> 5;
    GLDS(Ag0, (char*)As[0] + tid * 16);
    GLDS(Ag0 + 32, (char*)As[0] + tid * 16 + 4096);
    GLDS(Bg0, (char*)Bs[0] + tid * 16);
    GLDS(Bg0 + 32, (char*)Bs[0] + tid * 16 + 4096);

    for (int it = 0; it < nIter; ++it) {
        __syncthreads();
        if (it + 1 < nIter) {
            int kb = (it + 1) << 6;
            char* Ad = (char*)As[(it + 1) & 1] + tid * 16;
            char* Bd = (char*)Bs[(it + 1) & 1] + tid * 16;
            GLDS(Ag0 + kb, Ad);
            GLDS(Ag0 + kb + 32, Ad + 4096);
            GLDS(Bg0 + kb, Bd);
            GLDS(Bg0 + kb + 32, Bd + 4096);
        }
        const short* Ab = As[it & 1];
        const short* Bb = Bs[it & 1];
        s8v af[4], bfr[4];
#pragma unroll
        for (int i = 0; i < 4; ++i)
            af[i] = *(const s8v*)(Ab + ((size_t)quad * 128 + wr * 64 + i * 16 + ln) * 8);
#pragma unroll
        for (int j = 0; j < 4; ++j)
            bfr[j] = *(const s8v*)(Bb + ((size_t)quad * 128 + wc * 64 + j * 16 + ln) * 8);
#pragma unroll
        for (int i = 0; i < 4; ++i)
#pragma unroll
            for (int j = 0; j < 4; ++j)
                acc[i][j] = __builtin_amdgcn_mfma_f32_16x16x32_bf16(af[i], bfr[j], acc[i][j], 0, 0, 0);
    }

    int cn  = n0 + wc * 64 + ln;
    int cm0 = m0 + wr * 64 + quad * 4;
#pragma unroll
    for (int j = 0; j < 4; ++j) {
        int gn = cn + j * 16;
#pragma unroll
        for (int i = 0; i < 4; ++i)
#pragma unroll
            for (int r = 0; r < 4; ++r)
                Cf[(size_t)(cm0 + i * 16 + r) * N + gn] = acc[i][j][r];
    }
}

// ---------------- double-buffered MFMA flash attention (unchanged from R2) ------------
__global__ __launch_bounds__(256) void flash_attn_mfma_kernel(
    const unsigned short* __restrict__ qk,   // [NTOK][2048]  (q*scale | k per head)
    const unsigned short* __restrict__ vt,   // [B*1024][SEQ] (v transposed)
    unsigned short* __restrict__ ctx)        // [NTOK][EMB]
{
    int h  = blockIdx.x;
    int b  = blockIdx.z;
    int qt = b ? (int)blockIdx.y : ((int)gridDim.y - 1 - (int)blockIdx.y);
    int tid = threadIdx.x;
    int w = tid >> 6, lane = tid & 63;
    int quad = lane >> 4, ln = lane & 15;

    __shared__ short Kb2[2][4096];
    __shared__ short Vb2[2][4096];
    __shared__ short Ps[4][32 * 72];

    size_t qrow0 = (size_t)b * SEQ + (size_t)qt * 128;
    int wrow0 = w * 32;

    s8v qf[2][2];
#pragma unroll
    for (int mb = 0; mb < 2; ++mb)
#pragma unroll
        for (int ks = 0; ks < 2; ++ks)
            qf[mb][ks] = *(const s8v*)(qk + (qrow0 + wrow0 + mb * 16 + ln) * 2048
                                          + h * 64 + ks * 32 + quad * 8);

    float l_part[2][4];
    f4v o[2][4];
#pragma unroll
    for (int mb = 0; mb < 2; ++mb) {
#pragma unroll
        for (int r = 0; r < 4; ++r) l_part[mb][r] = 0.f;
#pragma unroll
        for (int db = 0; db < 4; ++db) {
            f4v z = {0.f, 0.f, 0.f, 0.f};
            o[mb][db] = z;
        }
    }

    const unsigned short* kb_p = qk + (size_t)b * SEQ * 2048 + 1024 + h * 64;
    const unsigned short* vb_p = vt + ((size_t)b * 1024 + h * 64) * SEQ;
    short* Pw = Ps[w];

    int rr = tid & 63;
    const unsigned short* Kg0 = kb_p + (size_t)rr * 2048 + (tid >> 6) * 8;
    const unsigned short* Vg0 = vb_p + (size_t)rr * 2048 + (tid >> 6) * 8;

    int ktn = 2 * qt + 2;
    int ktmax_w = (qt * 128 + wrow0 + 31) >> 6;

    GLDS(Kg0, (char*)Kb2[0] + tid * 16);
    GLDS(Kg0 + 32, (char*)Kb2[0] + tid * 16 + 4096);
    GLDS(Vg0, (char*)Vb2[0] + tid * 16);
    GLDS(Vg0 + 32, (char*)Vb2[0] + tid * 16 + 4096);

    for (int kt = 0; kt < ktn; ++kt) {
        BAR();
        bool pf = (kt + 1 < ktn);
        if (pf) {
            int nb_ = (kt + 1) & 1;
            const unsigned short* ks_ = Kg0 + (size_t)(kt + 1) * 64 * 2048;
            const unsigned short* vs_ = Vg0 + (kt + 1) * 64;
            GLDS(ks_, (char*)Kb2[nb_] + tid * 16);
            GLDS(ks_ + 32, (char*)Kb2[nb_] + tid * 16 + 4096);
            GLDS(vs_, (char*)Vb2[nb_] + tid * 16);
            GLDS(vs_ + 32, (char*)Vb2[nb_] + tid * 16 + 4096);
        }
        if (kt > ktmax_w) continue;
        if (pf) { VMCNT(8); } else { VMCNT(0); }

        const short* Kl = Kb2[kt & 1];
        const short* Vl = Vb2[kt & 1];

        f4v s[2][4];
#pragma unroll
        for (int mb = 0; mb < 2; ++mb)
#pragma unroll
            for (int nb = 0; nb < 4; ++nb) {
                f4v z = {0.f, 0.f, 0.f, 0.f};
                s[mb][nb] = z;
            }
#pragma unroll
        for (int ks = 0; ks < 2; ++ks)
#pragma unroll
            for (int nb = 0; nb < 4; ++nb) {
                s8v kfr = *(const s8v*)(Kl + ((size_t)(ks * 4 + quad) * 64 + nb * 16 + ln) * 8);
#pragma unroll
                for (int mb = 0; mb < 2; ++mb)
                    s[mb][nb] = __builtin_amdgcn_mfma_f32_16x16x32_bf16(qf[mb][ks], kfr, s[mb][nb], 0, 0, 0);
            }

        bool edge = (kt == ktmax_w);
#pragma unroll
        for (int mb = 0; mb < 2; ++mb) {
#pragma unroll
            for (int r = 0; r < 4; ++r) {
                int rloc = mb * 16 + quad * 4 + r;
                float p[4];
                if (!edge) {
#pragma unroll
                    for (int nb = 0; nb < 4; ++nb)
                        p[nb] = fast_exp2(s[mb][nb][r]);
                } else {
                    int grow = qt * 128 + wrow0 + rloc;
#pragma unroll
                    for (int nb = 0; nb < 4; ++nb) {
                        int key = kt * 64 + nb * 16 + ln;
                        float e = fast_exp2(s[mb][nb][r]);
                        p[nb] = (key > grow) ? 0.f : e;
                    }
                }
                l_part[mb][r] += (p[0] + p[1]) + (p[2] + p[3]);
#pragma unroll
                for (int nb = 0; nb < 4; ++nb)
                    Pw[rloc * 72 + nb * 16 + ln] = f2bf(p[nb]);
            }
        }

#pragma unroll
        for (int ks = 0; ks < 2; ++ks) {
            s8v pf_[2];
#pragma unroll
            for (int mb = 0; mb < 2; ++mb)
                pf_[mb] = *(const s8v*)(Pw + (mb * 16 + ln) * 72 + ks * 32 + quad * 8);
#pragma unroll
            for (int db = 0; db < 4; ++db) {
                s8v vfr = *(const s8v*)(Vl + ((size_t)(ks * 4 + quad) * 64 + db * 16 + ln) * 8);
#pragma unroll
                for (int mb = 0; mb < 2; ++mb)
                    o[mb][db] = __builtin_amdgcn_mfma_f32_16x16x32_bf16(pf_[mb], vfr, o[mb][db], 0, 0, 0);
            }
        }
    }

    asm volatile("s_waitcnt vmcnt(0)" ::: "memory");

#pragma unroll
    for (int mb = 0; mb < 2; ++mb)
#pragma unroll
        for (int r = 0; r < 4; ++r) {
            float l = l_part[mb][r];
#pragma unroll
            for (int msk = 1; msk < 16; msk <<= 1)
                l += __shfl_xor(l, msk);
            float inv = 1.0f / l;
            size_t row = qrow0 + wrow0 + mb * 16 + quad * 4 + r;
#pragma unroll
            for (int db = 0; db < 4; ++db)
                ctx[row * EMB + h * 64 + db * 16 + ln] = f2bf(o[mb][db][r] * inv);
        }
}

extern "C" void kernel_launch(void* const* d_in, const int* in_sizes, int n_in,
                              void* d_out, int out_size, void* d_ws, size_t ws_size,
                              hipStream_t stream) {
    const float* x    = (const float*)d_in[0];
    const float* Wq   = (const float*)d_in[1];
    const float* Wk   = (const float*)d_in[2];
    const float* Wv   = (const float*)d_in[3];
    const float* Wo   = (const float*)d_in[4];
    const float* bo   = (const float*)d_in[5];
    const float* W1   = (const float*)d_in[6];
    const float* b1   = (const float*)d_in[7];
    const float* W2   = (const float*)d_in[8];
    const float* b2   = (const float*)d_in[9];
    const float* ln1s = (const float*)d_in[10];
    const float* ln1b = (const float*)d_in[11];
    const float* ln2s = (const float*)d_in[12];
    const float* ln2b = (const float*)d_in[13];
    float* out = (float*)d_out;

    const size_t MiB = 1024 * 1024;
    uint8_t* w8 = (uint8_t*)d_ws;
    unsigned short* Wqkv_t = (unsigned short*)(w8);             //  0..6   [3072][1024]
    unsigned short* Wo_t   = (unsigned short*)(w8 +  6 * MiB);  //  6..8   [1024][1024]
    unsigned short* W1_t   = (unsigned short*)(w8 +  8 * MiB);  //  8..16  [4096][1024]
    unsigned short* W2_t   = (unsigned short*)(w8 + 16 * MiB);  // 16..24  [1024][4096]
    unsigned short* act_bf = (unsigned short*)(w8 + 24 * MiB);  // 24..32  h1/ctx/h2
    unsigned short* qk_bf  = (unsigned short*)(w8 + 32 * MiB);  // 32..48  [4096][2048]
    unsigned short* vt     = (unsigned short*)(w8 + 48 * MiB);  // 48..56  [2048][2048]
    float*          p0a    = (float*)(w8 + 32 * MiB);           // 32..48  (after attn)
    float*          p1a    = (float*)(w8 + 48 * MiB);           // 48..64
    unsigned short* u_bf   = (unsigned short*)(w8 + 32 * MiB);  // 32..64  (step 6+)
    float*          x1     = (float*)(w8 + 64 * MiB);           // 64..80
    float*          p0b    = (float*)(w8);                      //  0..16  (weights dead)
    float*          p1b    = (float*)(w8 + 80 * MiB);           // 80..96

    // 0) all weight converts in one dispatch
    tconv_all_kernel<<<3072, 256, 0, stream>>>(Wq, Wk, Wv, Wo, W1, W2,
                                               Wqkv_t, Wo_t, W1_t, W2_t);

    // 1) LN1 -> bf16
    ln_bf16_kernel<<<NTOK, 256, 0, stream>>>(x, ln1s, ln1b, act_bf);

    // 2) fused QKV (128^2, depth-2 pipeline; q prescaled, v -> vt)  768 blocks
    gemm_fused_kernel<<<(NTOK / 128) * (QKV_N / 128), 256, 0, stream>>>(
        act_bf, Wqkv_t, qk_bf, NTOK, QKV_N, EMB, nullptr, 0, 1, vt);

    // 3) double-buffered MFMA flash attention -> ctx bf16
    flash_attn_mfma_kernel<<<dim3(HEADS, SEQ / 128, BATCH), 256, 0, stream>>>(qk_bf, vt, act_bf);

    // 4+5) x1 = x + ctx @ Wo + bo (split-K2, R2-original); fused reduce+LN2
    gemm_bf16_kernel<<<dim3(EMB / 128, NTOK / 128, 2), 256, 0, stream>>>(
        act_bf, Wo_t, p0a, p1a, NTOK, EMB, EMB, 512);
    reduce_ln_kernel<<<NTOK, 256, 0, stream>>>(p0a, p1a, bo, x, x1, ln2s, ln2b, act_bf);

    // 6) u = gelu(h2 @ W1 + b1) -> bf16  (128^2, depth-2)  1024 blocks
    gemm_fused_kernel<<<(NTOK / 128) * (FF_DIM / 128), 256, 0, stream>>>(
        act_bf, W1_t, u_bf, NTOK, FF_DIM, EMB, b1, 1, 0, nullptr);

    // 7) out = x1 + u @ W2 + b2   (split-K2, R2-original)
    gemm_bf16_kernel<<<dim3(EMB / 128, NTOK / 128, 2), 256, 0, stream>>>(
        u_bf, W2_t, p0b, p1b, NTOK, EMB, FF_DIM, 2048);
    reduce_kernel<<<(NTOK * EMB) / 1024, 256, 0, stream>>>(p0b, p1b, b2, x1, out);
}

// Round 10
// 411.354 us; speedup vs baseline: 1.2995x; 1.0936x over previous
//
#include <hip/hip_runtime.h>
#include <hip/hip_bf16.h>
#include <math.h>

#define EMB 1024
#define HEADS 16
#define HEAD_DIM 64
#define FF_DIM 4096
#define SEQ 2048
#define BATCH 2
#define NTOK (BATCH * SEQ)   // 4096 rows
#define LN_EPS 1e-5f
#define QKV_N 3072
// fold softmax scale into q: 0.125 * log2(e)
#define Q_PRESCALE 0.18033688011112042f

typedef __attribute__((ext_vector_type(8))) short s8v;   // 8 bf16 (4 VGPRs)
typedef __attribute__((ext_vector_type(4))) float f4v;   // MFMA accumulator

__device__ __forceinline__ unsigned short f2bf(float f) {
    union { __hip_bfloat16 h; unsigned short u; } cv;
    cv.h = __float2bfloat16(f);
    return cv.u;
}

__device__ __forceinline__ float fast_exp2(float x) {
#if __has_builtin(__builtin_amdgcn_exp2f)
    return __builtin_amdgcn_exp2f(x);
#else
    return exp2f(x);
#endif
}

// gelu with exp2-based tanh (libm tanhf ~30 insts -> ~8; identical math:
// tanh(y) = 1 - 2/(exp(2y)+1); verified absmax-identical R6-R9)
__device__ __forceinline__ float gelu_f(float x) {
    const float c = 0.7978845608028654f;  // sqrt(2/pi)
    float y = c * (x + 0.044715f * x * x * x);
    float e = fast_exp2(y * 2.8853900817779268f);   // 2*log2(e)
    float t = 1.0f - 2.0f / (e + 1.0f);
    return 0.5f * x * (1.0f + t);
}

#define GLDS(gp, lp)                                                        \
    __builtin_amdgcn_global_load_lds(                                       \
        (const __attribute__((address_space(1))) void*)(gp),                \
        (__attribute__((address_space(3))) void*)(lp), 16, 0, 0)

// sync helpers (raw barrier: no compiler vmcnt(0) drain)
#define BAR()   do { __builtin_amdgcn_s_barrier(); __builtin_amdgcn_sched_barrier(0); } while (0)
#define LGKM0() do { asm volatile("s_waitcnt lgkmcnt(0)" ::: "memory"); __builtin_amdgcn_sched_barrier(0); } while (0)
#define VMCNT(n) do { asm volatile("s_waitcnt vmcnt(" #n ")" ::: "memory"); __builtin_amdgcn_sched_barrier(0); } while (0)

// ---------------- LayerNorm -> bf16 out ----------------------------------------------
__global__ __launch_bounds__(256) void ln_bf16_kernel(const float* __restrict__ x,
                                                      const float* __restrict__ scale,
                                                      const float* __restrict__ shift,
                                                      unsigned short* __restrict__ out) {
    int row = blockIdx.x;
    int tid = threadIdx.x;
    const float4 xv = ((const float4*)(x + (size_t)row * EMB))[tid];
    float s  = xv.x + xv.y + xv.z + xv.w;
    float ss = xv.x * xv.x + xv.y * xv.y + xv.z * xv.z + xv.w * xv.w;
    __shared__ float2 red[256];
    red[tid] = make_float2(s, ss);
    __syncthreads();
    for (int off = 128; off > 0; off >>= 1) {
        if (tid < off) {
            red[tid].x += red[tid + off].x;
            red[tid].y += red[tid + off].y;
        }
        __syncthreads();
    }
    float mean = red[0].x * (1.0f / EMB);
    float var  = red[0].y * (1.0f / EMB) - mean * mean;
    float rstd = rsqrtf(var + LN_EPS);
    float4 sc4 = ((const float4*)scale)[tid];
    float4 sh4 = ((const float4*)shift)[tid];
    ushort4 o;
    o.x = f2bf(sc4.x * (xv.x - mean) * rstd + sh4.x);
    o.y = f2bf(sc4.y * (xv.y - mean) * rstd + sh4.y);
    o.z = f2bf(sc4.z * (xv.z - mean) * rstd + sh4.z);
    o.w = f2bf(sc4.w * (xv.w - mean) * rstd + sh4.w);
    *(ushort4*)(out + (size_t)row * EMB + tid * 4) = o;
}

// ---------------- fused fp32 [K][N] -> bf16 [N][K] transpose-convert (ALL weights) ----
__device__ __forceinline__ void tconv_tile(const float* __restrict__ W,
                                           unsigned short* __restrict__ Wt,
                                           int K, int N, int bx, int by, int tid) {
    __shared__ float t[64][65];
    int n0 = bx * 64, k0 = by * 64;
#pragma unroll
    for (int it = 0; it < 4; ++it) {
        int f = tid + it * 256;
        int r = f >> 4, c = (f & 15) * 4;
        float4 w = *(const float4*)(W + (size_t)(k0 + r) * N + n0 + c);
        t[r][c] = w.x; t[r][c + 1] = w.y; t[r][c + 2] = w.z; t[r][c + 3] = w.w;
    }
    __syncthreads();
#pragma unroll
    for (int it = 0; it < 4; ++it) {
        int f = tid + it * 256;
        int rn = f >> 4, ck = (f & 15) * 4;
        ushort4 o;
        o.x = f2bf(t[ck + 0][rn]);
        o.y = f2bf(t[ck + 1][rn]);
        o.z = f2bf(t[ck + 2][rn]);
        o.w = f2bf(t[ck + 3][rn]);
        *(ushort4*)(Wt + (size_t)(n0 + rn) * K + k0 + ck) = o;
    }
}

__global__ __launch_bounds__(256) void tconv_all_kernel(
    const float* __restrict__ Wq, const float* __restrict__ Wk,
    const float* __restrict__ Wv, const float* __restrict__ Wo,
    const float* __restrict__ W1, const float* __restrict__ W2,
    unsigned short* __restrict__ Wqkv_t, unsigned short* __restrict__ Wo_t,
    unsigned short* __restrict__ W1_t, unsigned short* __restrict__ W2_t) {
    int b = blockIdx.x;
    int tid = threadIdx.x;
    if (b < 256)        tconv_tile(Wq, Wqkv_t,                      EMB, EMB,    b & 15, b >> 4, tid);
    else if (b < 512)   tconv_tile(Wk, Wqkv_t + (size_t)1024 * EMB, EMB, EMB,    (b - 256) & 15, (b - 256) >> 4, tid);
    else if (b < 768)   tconv_tile(Wv, Wqkv_t + (size_t)2048 * EMB, EMB, EMB,    (b - 512) & 15, (b - 512) >> 4, tid);
    else if (b < 1024)  tconv_tile(Wo, Wo_t,                        EMB, EMB,    (b - 768) & 15, (b - 768) >> 4, tid);
    else if (b < 2048)  tconv_tile(W1, W1_t,                        EMB, FF_DIM, (b - 1024) & 63, (b - 1024) >> 6, tid);
    else                tconv_tile(W2, W2_t,                        FF_DIM, EMB, (b - 2048) & 15, (b - 2048) >> 4, tid);
}

// ---------------- split-K reduce: out = p0 + p1 + bias + residual ---------------------
__global__ __launch_bounds__(256) void reduce_kernel(const float* __restrict__ p0,
                                                     const float* __restrict__ p1,
                                                     const float* __restrict__ bias,
                                                     const float* __restrict__ residual,
                                                     float* __restrict__ out) {
    size_t i4 = ((size_t)blockIdx.x * 256 + threadIdx.x) * 4;
    float4 a = *(const float4*)(p0 + i4);
    float4 b = *(const float4*)(p1 + i4);
    float4 r = *(const float4*)(residual + i4);
    int col = (int)(i4 & (EMB - 1));
    float4 bs = *(const float4*)(bias + col);
    float4 o;
    o.x = a.x + b.x + r.x + bs.x;
    o.y = a.y + b.y + r.y + bs.y;
    o.z = a.z + b.z + r.z + bs.z;
    o.w = a.w + b.w + r.w + bs.w;
    *(float4*)(out + i4) = o;
}

// ---------------- fused split-K reduce + LayerNorm ------------------------------------
__global__ __launch_bounds__(256) void reduce_ln_kernel(const float* __restrict__ p0,
                                                        const float* __restrict__ p1,
                                                        const float* __restrict__ bias,
                                                        const float* __restrict__ residual,
                                                        float* __restrict__ x1,
                                                        const float* __restrict__ scale,
                                                        const float* __restrict__ shift,
                                                        unsigned short* __restrict__ out) {
    int row = blockIdx.x;
    int tid = threadIdx.x;
    size_t i4 = (size_t)row * EMB + tid * 4;
    float4 a = *(const float4*)(p0 + i4);
    float4 b = *(const float4*)(p1 + i4);
    float4 r = *(const float4*)(residual + i4);
    float4 bs = *(const float4*)(bias + tid * 4);
    float4 xv;
    xv.x = a.x + b.x + r.x + bs.x;
    xv.y = a.y + b.y + r.y + bs.y;
    xv.z = a.z + b.z + r.z + bs.z;
    xv.w = a.w + b.w + r.w + bs.w;
    *(float4*)(x1 + i4) = xv;

    float s  = xv.x + xv.y + xv.z + xv.w;
    float ss = xv.x * xv.x + xv.y * xv.y + xv.z * xv.z + xv.w * xv.w;
    __shared__ float2 red[256];
    red[tid] = make_float2(s, ss);
    __syncthreads();
    for (int off = 128; off > 0; off >>= 1) {
        if (tid < off) {
            red[tid].x += red[tid + off].x;
            red[tid].y += red[tid + off].y;
        }
        __syncthreads();
    }
    float mean = red[0].x * (1.0f / EMB);
    float var  = red[0].y * (1.0f / EMB) - mean * mean;
    float rstd = rsqrtf(var + LN_EPS);
    float4 sc4 = ((const float4*)scale)[tid];
    float4 sh4 = ((const float4*)shift)[tid];
    ushort4 o;
    o.x = f2bf(sc4.x * (xv.x - mean) * rstd + sh4.x);
    o.y = f2bf(sc4.y * (xv.y - mean) * rstd + sh4.y);
    o.z = f2bf(sc4.z * (xv.z - mean) * rstd + sh4.z);
    o.w = f2bf(sc4.w * (xv.w - mean) * rstd + sh4.w);
    *(ushort4*)(out + i4) = o;
}

// ================= 8-phase 256x256 bf16 MFMA GEMM (R2-measured best for QKV/FFN1) =====
// Restored exactly from the 422us build. 256^2 tiles keep FETCH at 37 MB (vs 123 for
// 128^2) -- less L2/L3 thrash for the downstream flash kernel; era-consistent totals
// 422-428 across R1-R3 vs 443-475 for all 128^2 fused variants.
__global__ __launch_bounds__(512, 2) void gemm_8ph_kernel(
    const unsigned short* __restrict__ A,   // [M,K] bf16
    const unsigned short* __restrict__ Bt,  // [N,K] bf16
    unsigned short* __restrict__ Cb,        // bf16 out
    int M, int N, int K,
    const float* __restrict__ bias,
    int do_gelu, int qkv_mode,
    unsigned short* __restrict__ vt)
{
    __shared__ short lds[65536];   // 128 KiB: A at [0,64K), B at [64K,128K) bytes

    int tid = threadIdx.x;
    int w = tid >> 6, lane = tid & 63;
    int wr = w >> 2, wc = w & 3;          // wave rows wr*128.., cols wc*64..
    int quad = lane >> 4, ln = lane & 15;

    // XCD-bijective block swizzle (nwg % 8 == 0 for both call sites)
    int nbx = N >> 8;
    int nwg = (M >> 8) * nbx;
    int bid = (int)blockIdx.x;
    int swz = (nwg & 7) ? bid : ((bid & 7) * (nwg >> 3) + (bid >> 3));
    int by = swz / nbx, bx = swz - by * nbx;
    int m0 = by << 8, n0 = bx << 8;

    f4v acc[8][4];
#pragma unroll
    for (int i = 0; i < 8; ++i)
#pragma unroll
        for (int j = 0; j < 4; ++j) { f4v z = {0.f, 0.f, 0.f, 0.f}; acc[i][j] = z; }

    size_t Kby = (size_t)K << 1;
    size_t AhS = (size_t)128 * Kby;       // half-tile row-block stride (A and B)
    const char* AgC = (const char*)A + (size_t)(m0 + (tid & 127)) * Kby + (size_t)((tid >> 7) << 4);
    const char* BgC = (const char*)Bt + (size_t)(n0 + (tid & 127)) * Kby + (size_t)((tid >> 7) << 4);
    char* ldsC = (char*)lds;
    int tid16 = tid << 4;

    // frag read bases (shorts): A[buf][half=wr][kc=ks*4+quad][row=f*16+ln][8]
    const short* aRd = lds + wr * 8192 + quad * 1024 + ln * 8;
    const short* bRd = lds + 32768 + (wc >> 1) * 8192 + (wc & 1) * 512 + quad * 1024 + ln * 8;

#define STG_A(tb, h, b) do {                                                     \
    const char* s_ = AgC + (size_t)(h) * AhS + (size_t)(tb);                     \
    char* d_ = ldsC + (b) * 32768 + (h) * 16384 + tid16;                         \
    GLDS(s_, d_); GLDS(s_ + 64, d_ + 8192); } while (0)
#define STG_B(tb, h, b) do {                                                     \
    const char* s_ = BgC + (size_t)(h) * AhS + (size_t)(tb);                     \
    char* d_ = ldsC + 65536 + (b) * 32768 + (h) * 16384 + tid16;                 \
    GLDS(s_, d_); GLDS(s_ + 64, d_ + 8192); } while (0)
#define RD_A4(mg, b) do {                                                        \
    _Pragma("unroll") for (int f_ = 0; f_ < 4; ++f_) {                           \
        af[f_][0] = *(const s8v*)(aRd + (b) * 16384 + ((mg) * 4 + f_) * 128);    \
        af[f_][1] = *(const s8v*)(aRd + (b) * 16384 + 4096 + ((mg) * 4 + f_) * 128); } } while (0)
#define RD_B2(dst, ng, b) do {                                                   \
    _Pragma("unroll") for (int g_ = 0; g_ < 2; ++g_) {                           \
        dst[g_][0] = *(const s8v*)(bRd + (b) * 16384 + ((ng) * 2 + g_) * 128);   \
        dst[g_][1] = *(const s8v*)(bRd + (b) * 16384 + 4096 + ((ng) * 2 + g_) * 128); } } while (0)
#define MF_Q(mg, bsrc, ng) do {                                                  \
    __builtin_amdgcn_s_setprio(1);                                               \
    _Pragma("unroll") for (int f_ = 0; f_ < 4; ++f_)                             \
    _Pragma("unroll") for (int g_ = 0; g_ < 2; ++g_)                             \
    _Pragma("unroll") for (int k_ = 0; k_ < 2; ++k_)                             \
        acc[(mg) * 4 + f_][(ng) * 2 + g_] = __builtin_amdgcn_mfma_f32_16x16x32_bf16( \
            af[f_][k_], bsrc[g_][k_], acc[(mg) * 4 + f_][(ng) * 2 + g_], 0, 0, 0); \
    __builtin_amdgcn_s_setprio(0); } while (0)

    s8v af[4][2], bf0[2][2], bf1[2][2];

    // prologue: tile0 fully + tile1 B-halves (12 loads); wait keeps tile1 B in flight
    STG_A(0, 0, 0); STG_A(0, 1, 0);
    STG_B(0, 0, 0); STG_B(0, 1, 0);
    STG_B(128, 0, 1); STG_B(128, 1, 1);
    VMCNT(4);
    BAR();

    int nIter = K >> 7;   // K multiple of 128
    for (int it = 0; it < nIter; ++it) {
        size_t base = (size_t)it << 8;    // tile 2it byte offset in K
        bool pf = (it + 1 < nIter);

        // ---- K-tile T0 = 2it (buf0) ----
        RD_A4(0, 0); RD_B2(bf0, 0, 0);
        STG_A(base + 128, 0, 1);
        BAR(); LGKM0();
        MF_Q(0, bf0, 0);
        BAR();
        RD_B2(bf1, 1, 0);
        STG_A(base + 128, 1, 1);
        BAR(); LGKM0();
        MF_Q(0, bf1, 1);
        BAR();
        RD_A4(1, 0);
        if (pf) STG_B(base + 256, 0, 0);
        BAR(); LGKM0();
        MF_Q(1, bf0, 0);
        BAR();
        if (pf) STG_B(base + 256, 1, 0);
        BAR();
        MF_Q(1, bf1, 1);
        if (pf) { VMCNT(4); } else { VMCNT(0); }
        BAR();

        // ---- K-tile T1 = 2it+1 (buf1) ----
        RD_A4(0, 1); RD_B2(bf0, 0, 1);
        if (pf) STG_A(base + 256, 0, 0);
        BAR(); LGKM0();
        MF_Q(0, bf0, 0);
        BAR();
        RD_B2(bf1, 1, 1);
        if (pf) STG_A(base + 256, 1, 0);
        BAR(); LGKM0();
        MF_Q(0, bf1, 1);
        BAR();
        RD_A4(1, 1);
        if (pf) STG_B(base + 384, 0, 1);
        BAR(); LGKM0();
        MF_Q(1, bf0, 0);
        BAR();
        if (pf) STG_B(base + 384, 1, 1);
        BAR();
        MF_Q(1, bf1, 1);
        if (pf) VMCNT(4);
        BAR();
    }
#undef STG_A
#undef STG_B
#undef RD_A4
#undef RD_B2
#undef MF_Q

    // epilogue: C/D layout col=lane&15, row=(lane>>4)*4+reg
    int cn  = n0 + wc * 64 + ln;
    int cm0 = m0 + wr * 128 + quad * 4;

    if (qkv_mode) {
        if (n0 < 2048) {
            float sc = (n0 < 1024) ? Q_PRESCALE : 1.0f;
#pragma unroll
            for (int g = 0; g < 4; ++g) {
                int gn = cn + g * 16;
#pragma unroll
                for (int f = 0; f < 8; ++f)
#pragma unroll
                    for (int r = 0; r < 4; ++r)
                        Cb[(size_t)(cm0 + f * 16 + r) * 2048 + gn] = f2bf(acc[f][g][r] * sc);
            }
        } else {
#pragma unroll
            for (int g = 0; g < 4; ++g) {
                int gn = cn + g * 16 - 2048;       // h*64+d in [0,1024)
#pragma unroll
                for (int f = 0; f < 8; ++f) {
                    int gm0 = cm0 + f * 16;
                    int bb = gm0 >> 11, s0 = gm0 & 2047;
                    ushort4 pk;
                    pk.x = f2bf(acc[f][g][0]);
                    pk.y = f2bf(acc[f][g][1]);
                    pk.z = f2bf(acc[f][g][2]);
                    pk.w = f2bf(acc[f][g][3]);
                    *(ushort4*)(vt + ((size_t)bb * 1024 + gn) * SEQ + s0) = pk;
                }
            }
        }
        return;
    }

#pragma unroll
    for (int g = 0; g < 4; ++g) {
        int gn = cn + g * 16;
        float bj = bias ? bias[gn] : 0.f;
#pragma unroll
        for (int f = 0; f < 8; ++f)
#pragma unroll
            for (int r = 0; r < 4; ++r) {
                float vv = acc[f][g][r] + bj;
                if (do_gelu) vv = gelu_f(vv);
                Cb[(size_t)(cm0 + f * 16 + r) * N + gn] = f2bf(vv);
            }
    }
}

// ---------------- bf16 MFMA GEMM, double-buffered BK=32, 128x128 (split-K fp32) -------
// R2-original (81us W2 measured) -- 2D grid, __syncthreads loop.
__global__ __launch_bounds__(256) void gemm_bf16_kernel(
    const unsigned short* __restrict__ A,   // [M,K] bf16
    const unsigned short* __restrict__ Bt,  // [N,K] bf16
    float* __restrict__ Cf0,
    float* __restrict__ Cf1,
    int M, int N, int K, int Klen)
{
    __shared__ short As[2][4096];   // 8 KiB per buffer
    __shared__ short Bs[2][4096];

    int tid = threadIdx.x;
    int m0 = blockIdx.y * 128;
    int n0 = blockIdx.x * 128;
    int k0 = blockIdx.z * Klen;
    float* Cf = blockIdx.z ? Cf1 : Cf0;
    int wv = tid >> 6, lane = tid & 63;
    int wr = wv >> 1, wc = wv & 1;
    int quad = lane >> 4, ln = lane & 15;

    f4v acc[4][4];
#pragma unroll
    for (int i = 0; i < 4; ++i)
#pragma unroll
        for (int j = 0; j < 4; ++j) {
            f4v z = {0.f, 0.f, 0.f, 0.f};
            acc[i][j] = z;
        }

    int r0 = tid & 127;
    size_t Kby = (size_t)K << 1;
    const char* Ag0 = (const char*)A + (size_t)(m0 + r0) * Kby + (size_t)k0 * 2 + (tid >> 7) * 16;
    const char* Bg0 = (const char*)Bt + (size_t)(n0 + r0) * Kby + (size_t)k0 * 2 + (tid >> 7) * 16;

    int nIter = Klen >> 5;
    GLDS(Ag0, (char*)As[0] + tid * 16);
    GLDS(Ag0 + 32, (char*)As[0] + tid * 16 + 4096);
    GLDS(Bg0, (char*)Bs[0] + tid * 16);
    GLDS(Bg0 + 32, (char*)Bs[0] + tid * 16 + 4096);

    for (int it = 0; it < nIter; ++it) {
        __syncthreads();
        if (it + 1 < nIter) {
            int kb = (it + 1) << 6;
            char* Ad = (char*)As[(it + 1) & 1] + tid * 16;
            char* Bd = (char*)Bs[(it + 1) & 1] + tid * 16;
            GLDS(Ag0 + kb, Ad);
            GLDS(Ag0 + kb + 32, Ad + 4096);
            GLDS(Bg0 + kb, Bd);
            GLDS(Bg0 + kb + 32, Bd + 4096);
        }
        const short* Ab = As[it & 1];
        const short* Bb = Bs[it & 1];
        s8v af[4], bfr[4];
#pragma unroll
        for (int i = 0; i < 4; ++i)
            af[i] = *(const s8v*)(Ab + ((size_t)quad * 128 + wr * 64 + i * 16 + ln) * 8);
#pragma unroll
        for (int j = 0; j < 4; ++j)
            bfr[j] = *(const s8v*)(Bb + ((size_t)quad * 128 + wc * 64 + j * 16 + ln) * 8);
#pragma unroll
        for (int i = 0; i < 4; ++i)
#pragma unroll
            for (int j = 0; j < 4; ++j)
                acc[i][j] = __builtin_amdgcn_mfma_f32_16x16x32_bf16(af[i], bfr[j], acc[i][j], 0, 0, 0);
    }

    int cn  = n0 + wc * 64 + ln;
    int cm0 = m0 + wr * 64 + quad * 4;
#pragma unroll
    for (int j = 0; j < 4; ++j) {
        int gn = cn + j * 16;
#pragma unroll
        for (int i = 0; i < 4; ++i)
#pragma unroll
            for (int r = 0; r < 4; ++r)
                Cf[(size_t)(cm0 + i * 16 + r) * N + gn] = acc[i][j][r];
    }
}

// ---------------- double-buffered MFMA flash attention (R2 version) -------------------
__global__ __launch_bounds__(256) void flash_attn_mfma_kernel(
    const unsigned short* __restrict__ qk,   // [NTOK][2048]  (q*scale | k per head)
    const unsigned short* __restrict__ vt,   // [B*1024][SEQ] (v transposed)
    unsigned short* __restrict__ ctx)        // [NTOK][EMB]
{
    int h  = blockIdx.x;
    int b  = blockIdx.z;
    // balance: b=0 -> qt=15-y (long first), b=1 -> qt=y; pair work sums to 36 units
    int qt = b ? (int)blockIdx.y : ((int)gridDim.y - 1 - (int)blockIdx.y);
    int tid = threadIdx.x;
    int w = tid >> 6, lane = tid & 63;
    int quad = lane >> 4, ln = lane & 15;

    __shared__ short Kb2[2][4096];
    __shared__ short Vb2[2][4096];
    __shared__ short Ps[4][32 * 72];

    size_t qrow0 = (size_t)b * SEQ + (size_t)qt * 128;
    int wrow0 = w * 32;

    s8v qf[2][2];
#pragma unroll
    for (int mb = 0; mb < 2; ++mb)
#pragma unroll
        for (int ks = 0; ks < 2; ++ks)
            qf[mb][ks] = *(const s8v*)(qk + (qrow0 + wrow0 + mb * 16 + ln) * 2048
                                          + h * 64 + ks * 32 + quad * 8);

    float l_part[2][4];
    f4v o[2][4];
#pragma unroll
    for (int mb = 0; mb < 2; ++mb) {
#pragma unroll
        for (int r = 0; r < 4; ++r) l_part[mb][r] = 0.f;
#pragma unroll
        for (int db = 0; db < 4; ++db) {
            f4v z = {0.f, 0.f, 0.f, 0.f};
            o[mb][db] = z;
        }
    }

    const unsigned short* kb_p = qk + (size_t)b * SEQ * 2048 + 1024 + h * 64;
    const unsigned short* vb_p = vt + ((size_t)b * 1024 + h * 64) * SEQ;
    short* Pw = Ps[w];

    int rr = tid & 63;
    const unsigned short* Kg0 = kb_p + (size_t)rr * 2048 + (tid >> 6) * 8;
    const unsigned short* Vg0 = vb_p + (size_t)rr * 2048 + (tid >> 6) * 8;

    int ktn = 2 * qt + 2;
    int ktmax_w = (qt * 128 + wrow0 + 31) >> 6;

    GLDS(Kg0, (char*)Kb2[0] + tid * 16);
    GLDS(Kg0 + 32, (char*)Kb2[0] + tid * 16 + 4096);
    GLDS(Vg0, (char*)Vb2[0] + tid * 16);
    GLDS(Vg0 + 32, (char*)Vb2[0] + tid * 16 + 4096);

    for (int kt = 0; kt < ktn; ++kt) {
        BAR();
        bool pf = (kt + 1 < ktn);
        if (pf) {
            int nb_ = (kt + 1) & 1;
            const unsigned short* ks_ = Kg0 + (size_t)(kt + 1) * 64 * 2048;
            const unsigned short* vs_ = Vg0 + (kt + 1) * 64;
            GLDS(ks_, (char*)Kb2[nb_] + tid * 16);
            GLDS(ks_ + 32, (char*)Kb2[nb_] + tid * 16 + 4096);
            GLDS(vs_, (char*)Vb2[nb_] + tid * 16);
            GLDS(vs_ + 32, (char*)Vb2[nb_] + tid * 16 + 4096);
        }
        if (kt > ktmax_w) continue;
        // counted wait: force only THIS tile's loads (prefetch stays in flight)
        if (pf) { VMCNT(8); } else { VMCNT(0); }

        const short* Kl = Kb2[kt & 1];
        const short* Vl = Vb2[kt & 1];

        f4v s[2][4];
#pragma unroll
        for (int mb = 0; mb < 2; ++mb)
#pragma unroll
            for (int nb = 0; nb < 4; ++nb) {
                f4v z = {0.f, 0.f, 0.f, 0.f};
                s[mb][nb] = z;
            }
#pragma unroll
        for (int ks = 0; ks < 2; ++ks)
#pragma unroll
            for (int nb = 0; nb < 4; ++nb) {
                s8v kfr = *(const s8v*)(Kl + ((size_t)(ks * 4 + quad) * 64 + nb * 16 + ln) * 8);
#pragma unroll
                for (int mb = 0; mb < 2; ++mb)
                    s[mb][nb] = __builtin_amdgcn_mfma_f32_16x16x32_bf16(qf[mb][ks], kfr, s[mb][nb], 0, 0, 0);
            }

        bool edge = (kt == ktmax_w);   // mask needed only on the diagonal tile
#pragma unroll
        for (int mb = 0; mb < 2; ++mb) {
#pragma unroll
            for (int r = 0; r < 4; ++r) {
                int rloc = mb * 16 + quad * 4 + r;
                float p[4];
                if (!edge) {
#pragma unroll
                    for (int nb = 0; nb < 4; ++nb)
                        p[nb] = fast_exp2(s[mb][nb][r]);
                } else {
                    int grow = qt * 128 + wrow0 + rloc;
#pragma unroll
                    for (int nb = 0; nb < 4; ++nb) {
                        int key = kt * 64 + nb * 16 + ln;
                        float e = fast_exp2(s[mb][nb][r]);
                        p[nb] = (key > grow) ? 0.f : e;
                    }
                }
                l_part[mb][r] += (p[0] + p[1]) + (p[2] + p[3]);
#pragma unroll
                for (int nb = 0; nb < 4; ++nb)
                    Pw[rloc * 72 + nb * 16 + ln] = f2bf(p[nb]);
            }
        }

#pragma unroll
        for (int ks = 0; ks < 2; ++ks) {
            s8v pf_[2];
#pragma unroll
            for (int mb = 0; mb < 2; ++mb)
                pf_[mb] = *(const s8v*)(Pw + (mb * 16 + ln) * 72 + ks * 32 + quad * 8);
#pragma unroll
            for (int db = 0; db < 4; ++db) {
                s8v vfr = *(const s8v*)(Vl + ((size_t)(ks * 4 + quad) * 64 + db * 16 + ln) * 8);
#pragma unroll
                for (int mb = 0; mb < 2; ++mb)
                    o[mb][db] = __builtin_amdgcn_mfma_f32_16x16x32_bf16(pf_[mb], vfr, o[mb][db], 0, 0, 0);
            }
        }
    }

    // drain outstanding GLDS before epilogue/exit (skipping waves have loads in flight)
    asm volatile("s_waitcnt vmcnt(0)" ::: "memory");

#pragma unroll
    for (int mb = 0; mb < 2; ++mb)
#pragma unroll
        for (int r = 0; r < 4; ++r) {
            float l = l_part[mb][r];
#pragma unroll
            for (int msk = 1; msk < 16; msk <<= 1)
                l += __shfl_xor(l, msk);
            float inv = 1.0f / l;
            size_t row = qrow0 + wrow0 + mb * 16 + quad * 4 + r;
#pragma unroll
            for (int db = 0; db < 4; ++db)
                ctx[row * EMB + h * 64 + db * 16 + ln] = f2bf(o[mb][db][r] * inv);
        }
}

extern "C" void kernel_launch(void* const* d_in, const int* in_sizes, int n_in,
                              void* d_out, int out_size, void* d_ws, size_t ws_size,
                              hipStream_t stream) {
    const float* x    = (const float*)d_in[0];
    const float* Wq   = (const float*)d_in[1];
    const float* Wk   = (const float*)d_in[2];
    const float* Wv   = (const float*)d_in[3];
    const float* Wo   = (const float*)d_in[4];
    const float* bo   = (const float*)d_in[5];
    const float* W1   = (const float*)d_in[6];
    const float* b1   = (const float*)d_in[7];
    const float* W2   = (const float*)d_in[8];
    const float* b2   = (const float*)d_in[9];
    const float* ln1s = (const float*)d_in[10];
    const float* ln1b = (const float*)d_in[11];
    const float* ln2s = (const float*)d_in[12];
    const float* ln2b = (const float*)d_in[13];
    float* out = (float*)d_out;

    const size_t MiB = 1024 * 1024;
    uint8_t* w8 = (uint8_t*)d_ws;
    unsigned short* Wqkv_t = (unsigned short*)(w8);             //  0..6   [3072][1024]
    unsigned short* Wo_t   = (unsigned short*)(w8 +  6 * MiB);  //  6..8   [1024][1024]
    unsigned short* W1_t   = (unsigned short*)(w8 +  8 * MiB);  //  8..16  [4096][1024]
    unsigned short* W2_t   = (unsigned short*)(w8 + 16 * MiB);  // 16..24  [1024][4096]
    unsigned short* act_bf = (unsigned short*)(w8 + 24 * MiB);  // 24..32  h1/ctx/h2
    unsigned short* qk_bf  = (unsigned short*)(w8 + 32 * MiB);  // 32..48  [4096][2048]
    unsigned short* vt     = (unsigned short*)(w8 + 48 * MiB);  // 48..56  [2048][2048]
    float*          p0a    = (float*)(w8 + 32 * MiB);           // 32..48  (after attn)
    float*          p1a    = (float*)(w8 + 48 * MiB);           // 48..64
    unsigned short* u_bf   = (unsigned short*)(w8 + 32 * MiB);  // 32..64  (step 6+)
    float*          x1     = (float*)(w8 + 64 * MiB);           // 64..80
    float*          p0b    = (float*)(w8);                      //  0..16  (weights dead)
    float*          p1b    = (float*)(w8 + 80 * MiB);           // 80..96

    // 0) all weight converts in one dispatch
    tconv_all_kernel<<<3072, 256, 0, stream>>>(Wq, Wk, Wv, Wo, W1, W2,
                                               Wqkv_t, Wo_t, W1_t, W2_t);

    // 1) LN1 -> bf16
    ln_bf16_kernel<<<NTOK, 256, 0, stream>>>(x, ln1s, ln1b, act_bf);

    // 2) fused QKV (8-phase 256x256; q prescaled, q/k row-major bf16, v -> vt)
    gemm_8ph_kernel<<<(NTOK / 256) * (QKV_N / 256), 512, 0, stream>>>(
        act_bf, Wqkv_t, qk_bf, NTOK, QKV_N, EMB, nullptr, 0, 1, vt);

    // 3) double-buffered MFMA flash attention -> ctx bf16
    flash_attn_mfma_kernel<<<dim3(HEADS, SEQ / 128, BATCH), 256, 0, stream>>>(qk_bf, vt, act_bf);

    // 4+5) x1 = x + ctx @ Wo + bo (split-K2); fused reduce+LN2
    gemm_bf16_kernel<<<dim3(EMB / 128, NTOK / 128, 2), 256, 0, stream>>>(
        act_bf, Wo_t, p0a, p1a, NTOK, EMB, EMB, 512);
    reduce_ln_kernel<<<NTOK, 256, 0, stream>>>(p0a, p1a, bo, x, x1, ln2s, ln2b, act_bf);

    // 6) u = gelu(h2 @ W1 + b1) -> bf16  (8-phase 256x256)
    gemm_8ph_kernel<<<(NTOK / 256) * (FF_DIM / 256), 512, 0, stream>>>(
        act_bf, W1_t, u_bf, NTOK, FF_DIM, EMB, b1, 1, 0, nullptr);

    // 7) out = x1 + u @ W2 + b2   (split-K2)
    gemm_bf16_kernel<<<dim3(EMB / 128, NTOK / 128, 2), 256, 0, stream>>>(
        u_bf, W2_t, p0b, p1b, NTOK, EMB, FF_DIM, 2048);
    reduce_kernel<<<(NTOK * EMB) / 1024, 256, 0, stream>>>(p0b, p1b, b2, x1, out);
}